// Round 12
// baseline (18462.167 us; speedup 1.0000x reference)
//
#include <hip/hip_runtime.h>
#include <math.h>

#define BB 128   // batch
#define TT 256   // time
#define DD 256   // input dims
#define UU 512   // units
#define RR 512   // ladder order

// ws layout (floats), row-major activations:
//   X0 [128][512] @ 0        x_j lives in X[j&1]
//   X1 [128][512] @ 65536
//   M  [128][256] @ 131072   m_t while combo(t) runs
#define OFF_X0 0
#define OFF_X1 65536
#define OFF_M  131072
#define WS_FLT 163840
#define WS_NEED_BYTES (WS_FLT * 4)

// LDS layout (floats), pad-10 transposed tiles ([k][10], rows 0..7 used).
// h-part: HT(h_{t-1}) 5120 | XT(x_t) 5120 | MT(m_t) 2560 | FM(wfm) 256 = 13056 fl = 52.2KB
// x-part: XT(x_t) @0 5120 | UT(u) @5120 2560
#define L_HT 0
#define L_XT 5120
#define L_MT 10240
#define L_FM 12800
#define L_CFLT 13056

__global__ __launch_bounds__(256) void zero_kernel(float* __restrict__ p, int n)
{
    int i = blockIdx.x * 256 + threadIdx.x;
    if (i < n) p[i] = 0.0f;
}

// combo(t): 256 blocks x 256 threads.
//   bid<128: h-part, tile 8r x 64c:  h_t = tanhf(((aH+aX)+aF)+by)      (t>=0)
//   bid>=128: x-part, tile 8r x 64c: x_{t+1} = aA + aB                  (t<=254)
// cg = bid&7 (XCD-aligned col slice), rg = (bid&127)>>3 (16 row tiles of 8).
// Wave wv=tid>>6 handles rows o=wv*2, o+1; lane = weight column.
// Activations staged in LDS transposed [k][10]; all 64 lanes read the same
// address -> broadcast, conflict-free; one ds_read_b64 per matrix per k.
// Bitwise contract (= np ref, proven r7/r8): each dot = ascending-k
// single-accumulator fmaf chain from 0.0f; u = inp+m (one add);
// f = wfm*m (one mul); x = aA+aB (one add); z = ((aH+aX)+aF)+by.
__global__ __launch_bounds__(256) void combo_kernel(
    const float* __restrict__ inputs, const float* __restrict__ wfm,
    const float* __restrict__ by,     const float* __restrict__ WyhT,
    const float* __restrict__ WyxT,   const float* __restrict__ WyfT,
    const float* __restrict__ AT,     const float* __restrict__ BT,
    const float* __restrict__ xin,    // x_t
    const float* __restrict__ m,      // m_t
    float* __restrict__ xout,         // x_{t+1}
    float* __restrict__ out, int t)
{
    __shared__ float lds[L_CFLT];
    const int tid  = threadIdx.x;
    const int bid  = blockIdx.x;
    const int lane = tid & 63;
    const int wv   = tid >> 6;
    const bool is_h = bid < 128;
    const int b    = bid & 127;
    const int cg   = b & 7;
    const int rg   = b >> 3;
    const int R0   = rg * 8;
    const int c    = cg * 64 + lane;
    const int o    = wv * 2;             // this thread's row pair within tile

    if (is_h) {
        if (t < 0) return;
        // ---- stage h_{t-1}, x_t, m_t, wfm ----
        for (int i = tid; i < 8 * 512; i += 256) {
            int rr = i >> 9, k = i & 511;
            lds[L_HT + k * 10 + rr] = (t == 0) ? 0.0f
                : out[((R0 + rr) * TT + (t - 1)) * UU + k];
            lds[L_XT + k * 10 + rr] = xin[(R0 + rr) * RR + k];
        }
        for (int i = tid; i < 8 * 256; i += 256) {
            int rr = i >> 8, d = i & 255;
            lds[L_MT + d * 10 + rr] = m[(R0 + rr) * DD + d];
        }
        if (tid < 256) lds[L_FM + tid] = wfm[tid];
        __syncthreads();

        float ah0 = 0.0f, ah1 = 0.0f, ax0 = 0.0f, ax1 = 0.0f;
        #pragma unroll 16
        for (int k = 0; k < UU; ++k) {
            float wh = WyhT[k * UU + c];
            float wx = WyxT[k * UU + c];
            float2 hp = *reinterpret_cast<const float2*>(&lds[L_HT + k * 10 + o]);
            float2 xp = *reinterpret_cast<const float2*>(&lds[L_XT + k * 10 + o]);
            ah0 = fmaf(hp.x, wh, ah0);
            ah1 = fmaf(hp.y, wh, ah1);
            ax0 = fmaf(xp.x, wx, ax0);
            ax1 = fmaf(xp.y, wx, ax1);
        }
        float af0 = 0.0f, af1 = 0.0f;
        #pragma unroll 16
        for (int d = 0; d < DD; ++d) {
            float wf = WyfT[d * UU + c];
            float2 mp = *reinterpret_cast<const float2*>(&lds[L_MT + d * 10 + o]);
            float fm = lds[L_FM + d];
            af0 = fmaf(fm * mp.x, wf, af0);   // f = wfm*m (one mul), own chain
            af1 = fmaf(fm * mp.y, wf, af1);
        }
        float z0 = ((ah0 + ax0) + af0) + by[c];
        float z1 = ((ah1 + ax1) + af1) + by[c];
        out[((R0 + o) * TT + t) * UU + c]     = tanhf(z0);
        out[((R0 + o + 1) * TT + t) * UU + c] = tanhf(z1);
    } else {
        if (t >= TT - 1) return;
        // ---- stage x_t and u = inp_{t+1} + m_t ----
        for (int i = tid; i < 8 * 512; i += 256) {
            int rr = i >> 9, k = i & 511;
            lds[0 + k * 10 + rr] = xin[(R0 + rr) * RR + k];   // XT @ 0
        }
        for (int i = tid; i < 8 * 256; i += 256) {
            int rr = i >> 8, d = i & 255;
            lds[5120 + d * 10 + rr] =
                inputs[((R0 + rr) * TT + (t + 1)) * DD + d]
                + m[(R0 + rr) * DD + d];                 // u, one f32 add
        }
        __syncthreads();

        float a0 = 0.0f, a1 = 0.0f;
        #pragma unroll 16
        for (int k = 0; k < RR; ++k) {
            float wA = AT[k * RR + c];
            float2 xp = *reinterpret_cast<const float2*>(&lds[0 + k * 10 + o]);
            a0 = fmaf(xp.x, wA, a0);
            a1 = fmaf(xp.y, wA, a1);
        }
        float b0 = 0.0f, b1 = 0.0f;
        #pragma unroll 16
        for (int d = 0; d < DD; ++d) {
            float wB = BT[d * RR + c];
            float2 up = *reinterpret_cast<const float2*>(&lds[5120 + d * 10 + o]);
            b0 = fmaf(up.x, wB, b0);
            b1 = fmaf(up.y, wB, b1);
        }
        xout[(R0 + o) * RR + c]     = a0 + b0;    // dot + dot, one add
        xout[(R0 + o + 1) * RR + c] = a1 + b1;
    }
}

// m_{t+1} = x_{t+1} @ CT: 64 blocks x 256 threads, tile 8r x 64c.
// cg = bid&3 (cols 0..255), rg = bid>>2 (0..15).
__global__ __launch_bounds__(256) void m_kernel(
    const float* __restrict__ CT, const float* __restrict__ x,
    float* __restrict__ m)
{
    __shared__ float sXT[512 * 10];   // [k][10] pad layout, k*10+rr  (FIXED size: was OOB in r11)
    const int tid  = threadIdx.x;
    const int bid  = blockIdx.x;
    const int lane = tid & 63;
    const int wv   = tid >> 6;
    const int cg   = bid & 3;
    const int rg   = bid >> 2;
    const int R0   = rg * 8;
    const int c    = cg * 64 + lane;
    const int o    = wv * 2;

    for (int i = tid; i < 8 * 512; i += 256) {
        int rr = i >> 9, k = i & 511;
        sXT[k * 10 + rr] = x[(R0 + rr) * RR + k];
    }
    __syncthreads();

    float a0 = 0.0f, a1 = 0.0f;
    #pragma unroll 16
    for (int k = 0; k < RR; ++k) {
        float wC = CT[k * DD + c];
        float2 xp = *reinterpret_cast<const float2*>(&sXT[k * 10 + o]);
        a0 = fmaf(xp.x, wC, a0);
        a1 = fmaf(xp.y, wC, a1);
    }
    m[(R0 + o) * DD + c]     = a0;
    m[(R0 + o + 1) * DD + c] = a1;
}

__global__ __launch_bounds__(64) void sentinel_kernel(float* __restrict__ out, float v)
{
    if (threadIdx.x == 0 && blockIdx.x == 0) out[0] = v;
}

extern "C" void kernel_launch(void* const* d_in, const int* in_sizes, int n_in,
                              void* d_out, int out_size, void* d_ws, size_t ws_size,
                              hipStream_t stream)
{
    const float* inputs = (const float*)d_in[0];
    const float* wfm    = (const float*)d_in[1];
    const float* WyhT   = (const float*)d_in[2];
    const float* WyxT   = (const float*)d_in[3];
    const float* WyfT   = (const float*)d_in[4];
    const float* by     = (const float*)d_in[5];
    const float* AT     = (const float*)d_in[6];
    const float* BT     = (const float*)d_in[7];
    const float* CT     = (const float*)d_in[8];
    float* out = (float*)d_out;
    float* ws  = (float*)d_ws;

    // Environment sentinels (absmax reveals code if triggered).
    double code = 0.0;
    static const int exp_sizes[9] = {8388608, 256, 262144, 262144, 131072,
                                     512, 262144, 131072, 131072};
    if (n_in != 9) {
        code = 3.0e6 + n_in;
    } else {
        for (int i = 0; i < 9; ++i)
            if (in_sizes[i] != exp_sizes[i]) { code = 2.0e6 + i * 1.0e4; break; }
    }
    if (code == 0.0 && out_size != BB * TT * UU)
        code = 4.0e6 + (double)(out_size / 10000);
    if (code == 0.0 && ws_size < (size_t)WS_NEED_BYTES)
        code = 1.0e6 + (double)(ws_size / 1024);
    if (code != 0.0) {
        sentinel_kernel<<<1, 64, 0, stream>>>(out, (float)code);
        return;
    }

    float* X0 = ws + OFF_X0;
    float* X1 = ws + OFF_X1;
    float* M  = ws + OFF_M;

    // Zero X0/X1/M: x_{-1} (X1) and m_{-1} (M) must be exact 0.
    zero_kernel<<<(WS_FLT + 255) / 256, 256, 0, stream>>>(ws, WS_FLT);

    // t = -1: x-part computes x_0 (h-part self-disables); then m_0.
    // t = 0..254: combo(t) = { h_t ; x_{t+1} }, then m_{t+1}.
    // t = 255: h_255 only (x-part self-disables).
    for (int t = -1; t < TT; ++t) {
        const float* xc = (t & 1) ? X1 : X0;          // x_t  (t=-1 -> X1 zeros)
        float*       xn = ((t + 1) & 1) ? X1 : X0;    // x_{t+1}
        combo_kernel<<<256, 256, 0, stream>>>(inputs, wfm, by, WyhT, WyxT, WyfT,
                                              AT, BT, xc, M, xn, out, t);
        if (t < TT - 1)
            m_kernel<<<64, 256, 0, stream>>>(CT, xn, M);
    }
}